// Round 6
// baseline (1603.059 us; speedup 1.0000x reference)
//
#include <hip/hip_runtime.h>
#include <hip/hip_bf16.h>

#define N0 300000
#define N1 60000
#define N2 6000
#define E1 1200000
#define E2 300000
#define D 128
#define DO 64

#define WL_CAP 32768
#define UC_CAP 256
#define GRID 1024
#define BLK 256

typedef __attribute__((ext_vector_type(8))) short bfrag8;
typedef __attribute__((ext_vector_type(4))) float f32x4;

__device__ __forceinline__ float bf2f(unsigned int u) {
    union { unsigned int i; float f; } c; c.i = u << 16; return c.f;
}
__device__ __forceinline__ unsigned short f2bf(float f) {
    return __bfloat16_as_ushort(__float2bfloat16(f));
}

// device-scope tree barrier: 64 leaf counters -> root -> flag. State zeroed by k_pre.
__device__ __forceinline__ void gbar(int i, int* __restrict__ leaf,
                                     int* __restrict__ root, int* __restrict__ flag) {
    __threadfence();
    __syncthreads();
    if (threadIdx.x == 0) {
        int l = blockIdx.x & 63;
        int lo = __hip_atomic_fetch_add(&leaf[i * 64 + l], 1,
                                        __ATOMIC_ACQ_REL, __HIP_MEMORY_SCOPE_AGENT);
        if (lo == (GRID / 64) - 1) {
            int ro = __hip_atomic_fetch_add(&root[i], 1,
                                            __ATOMIC_ACQ_REL, __HIP_MEMORY_SCOPE_AGENT);
            if (ro == 63)
                __hip_atomic_store(&flag[i], 1, __ATOMIC_RELEASE, __HIP_MEMORY_SCOPE_AGENT);
        }
        while (__hip_atomic_load(&flag[i], __ATOMIC_ACQUIRE, __HIP_MEMORY_SCOPE_AGENT) == 0)
            __builtin_amdgcn_s_sleep(4);
    }
    __syncthreads();
}

// ---- zero accumulators + barrier state (every call; graph-replay safe) ----
__global__ void k_pre(float* __restrict__ statsfix, int* __restrict__ cnt,
                      int* __restrict__ nuc, int* __restrict__ ehist,
                      int* __restrict__ bar) {
    int b = blockIdx.x, t = threadIdx.x;
    if (b == 0) {
        statsfix[t] = 0.f;
        if (t == 0) { *cnt = 0; *nuc = 0; }
        for (int i = t; i < 336; i += 256) bar[i] = 0;
    }
    int hi = (b + 1) * 750; if (hi > N2) hi = N2;
    for (int i = b * 750 + t; i < hi; i += 256) ehist[i] = 0;
}

__global__ void __launch_bounds__(BLK, 4) k_main(
        const float* __restrict__ x, const int* __restrict__ src1,
        const int* __restrict__ dst1, const int* __restrict__ et1,
        const int* __restrict__ src2, const int* __restrict__ dst2,
        const int* __restrict__ et2, const int* __restrict__ hmap,
        const float* __restrict__ hist, const float* __restrict__ W1,
        const float* __restrict__ Wself1, const float* __restrict__ b1,
        const float* __restrict__ gamma, const float* __restrict__ beta,
        const float* __restrict__ W2, const float* __restrict__ Wself2,
        const float* __restrict__ b2,
        unsigned short* __restrict__ hb, unsigned short* __restrict__ aggb,
        unsigned short* __restrict__ BF, float* __restrict__ hfix,
        int* __restrict__ uc_node, int* __restrict__ uc_slot,
        int* __restrict__ epay, int* __restrict__ rs, int* __restrict__ rs2,
        float* __restrict__ psum, float* __restrict__ statsfix,
        int* __restrict__ cnt, int* __restrict__ nuc, int* __restrict__ ehist,
        int* __restrict__ list, float* __restrict__ params,
        int* __restrict__ bar, float* __restrict__ out) {
    __shared__ float smem[2048];
    __shared__ int part[256];
    int b = blockIdx.x, tid = threadIdx.x;
    int* leaf = bar; int* root = bar + 320; int* flag = bar + 328;

    // ===== Phase B: [0,256) init hb + stats partials; [256,1024) scan+hist =====
    if (b < 256) {
        int lane = tid & 63, q = tid & 31;
        float a1[4] = {0.f,0.f,0.f,0.f}, a2[4] = {0.f,0.f,0.f,0.f};
        for (int vb = b; vb < 1875; vb += 256) {
#pragma unroll
            for (int it = 0; it < 4; it++) {
                int idx = (vb * 4 + it) * 256 + tid;
                int node = idx >> 5;
                int m = hmap[node];
                float v[4];
                if (m >= 0) {
                    float4 hv = ((const float4*)hist)[m * 32 + q];
                    v[0] = hv.x; v[1] = hv.y; v[2] = hv.z; v[3] = hv.w;
                } else {
                    int slot = -1;
                    if (q == 0) {
                        slot = atomicAdd(nuc, 1);
                        if (slot < UC_CAP) { uc_slot[node] = slot; uc_node[slot] = node; }
                    }
                    slot = __shfl(slot, lane & 32, 64);
#pragma unroll
                    for (int j = 0; j < 4; j++) v[j] = b1[q * 4 + j];
                    for (int k = 0; k < D; k++) {
                        float xv = x[(size_t)node * D + k];
#pragma unroll
                        for (int j = 0; j < 4; j++) v[j] += xv * Wself1[k * D + q * 4 + j];
                    }
                    if (slot >= 0 && slot < UC_CAP) {
#pragma unroll
                        for (int j = 0; j < 4; j++) hfix[slot * D + q * 4 + j] = v[j];
                    }
                }
#pragma unroll
                for (int j = 0; j < 4; j++) { a1[j] += v[j]; a2[j] += v[j] * v[j]; }
                union { unsigned short s[4]; uint2 u; } o;
#pragma unroll
                for (int j = 0; j < 4; j++) o.s[j] = f2bf(v[j]);
                *(uint2*)(hb + (size_t)idx * 4) = o.u;
            }
        }
#pragma unroll
        for (int j = 0; j < 4; j++) { smem[tid * 4 + j] = a1[j]; smem[1024 + tid * 4 + j] = a2[j]; }
        __syncthreads();
        if (tid < 128) {
            int qq = tid >> 2, jj = tid & 3;
            float S = 0.f, SS = 0.f;
#pragma unroll
            for (int g = 0; g < 8; g++) {
                int src = (qq + 32 * g) * 4 + jj;
                S += smem[src]; SS += smem[1024 + src];
            }
            psum[b * 256 + tid] = S;
            psum[b * 256 + 128 + tid] = SS;
        }
    } else {
        for (int vb = b - 256; vb < 4688; vb += 768) {
            int e = vb * 256 + tid;
            if (e < E2) atomicAdd(&ehist[dst2[e]], 1);
            if (e < E1 && hmap[dst1[e]] < 0) {
                int i = atomicAdd(cnt, 1);
                if (i < WL_CAP) list[i] = e;
            }
        }
    }
    gbar(0, leaf, root, flag);

    // ===== Phase C: worklist edges (rare) =====
    if (b < 16) {
        int c = tid & 127, half = tid >> 7;
        int n = *cnt; if (n > WL_CAP) n = WL_CAP;
        for (int i = b * 2 + half; i < n; i += 32) {
            int e = list[i];
            int s = src1[e], d = dst1[e], t = et1[e];
            int slot = uc_slot[d];
            if (slot < 0 || slot >= UC_CAP) continue;
            float acc = 0.f;
            for (int k = 0; k < D; k++) acc += x[(size_t)s * D + k] * W1[(t * D + k) * D + c];
            float old = atomicAdd(&hfix[slot * D + c], acc);
            atomicAdd(&statsfix[c], acc);
            atomicAdd(&statsfix[128 + c], 2.f * old * acc + acc * acc);
        }
    }
    gbar(1, leaf, root, flag);

    // ===== Phase D: params | escan | bfrag | uc-copy =====
    if (b == 0) {
        if (tid < 128) {
            float S = statsfix[tid], SS = statsfix[128 + tid];
            for (int r = 0; r < 256; r++) {
                S += psum[r * 256 + tid];
                SS += psum[r * 256 + 128 + tid];
            }
            float mean = S / (float)N1;
            float var = SS / (float)N1 - mean * mean;
            float sc = gamma[tid] * rsqrtf(var + 1e-5f);
            params[tid] = sc;
            params[128 + tid] = beta[tid] - mean * sc;
        }
    } else if (b == 1) {
        int lo = tid * 24, hi = lo + 24; if (hi > N2) hi = N2;
        int s = 0;
        for (int i = lo; i < hi; i++) s += ehist[i];
        part[tid] = s;
        __syncthreads();
        if (tid == 0) {
            int a = 0;
            for (int i = 0; i < 256; i++) { int v = part[i]; part[i] = a; a += v; }
            rs[N2] = a;
        }
        __syncthreads();
        int a = part[tid];
        for (int i = lo; i < hi; i++) { rs[i] = a; rs2[i] = a; a += ehist[i]; }
    } else if (b < 162) {
        int idx = (b - 2) * 256 + tid;           // 40960 exactly
        int j = idx & 7, lane = (idx >> 3) & 63, sub = (idx >> 9) & 15, g = idx >> 13;
        int kt = sub >> 2, ct = sub & 3;
        int k = kt * 32 + (lane >> 4) * 8 + j;
        int col = ct * 16 + (lane & 15);
        float v = (g < 4) ? W2[(g * D + k) * DO + col] : Wself2[k * DO + col];
        BF[idx] = f2bf(v);
    } else if (b < 170) {
        int n = *nuc; if (n > UC_CAP) n = UC_CAP;
        int c = tid & 127, sub = tid >> 7;
        for (int slot = (b - 162) * 2 + sub; slot < n; slot += 16)
            hb[(size_t)uc_node[slot] * D + c] = f2bf(hfix[slot * D + c]);
    }
    gbar(2, leaf, root, flag);

    // ===== Phase E: CSR scatter =====
    for (int e = b * 256 + tid; e < E2; e += GRID * 256) {
        int d = dst2[e];
        int pos = atomicAdd(&rs2[d], 1);
        epay[pos] = src2[e] | (et2[e] << 16);
    }
    gbar(3, leaf, root, flag);

    // ===== Phase F: aggregate (block-per-dst, grid-stride) =====
    {
        int wave = tid >> 6, lane = tid & 63;
        float sc0 = params[2 * lane],     sh0 = params[128 + 2 * lane];
        float sc1 = params[2 * lane + 1], sh1 = params[128 + 2 * lane + 1];
        const unsigned int* hbu = (const unsigned int*)hb;
        unsigned int* aggbu = (unsigned int*)aggb;
        for (int d = b; d < N2; d += GRID) {
            float acc[4][2] = {};
            int j0 = rs[d], j1 = rs[d + 1];
            int j = j0 + wave;
#define AGG_ACC(P, V) { \
    int t_ = (P) >> 16; \
    float f0_ = fmaxf(bf2f((V) & 0xffff) * sc0 + sh0, 0.f); \
    float f1_ = fmaxf(bf2f((V) >> 16) * sc1 + sh1, 0.f); \
    acc[0][0] += (t_ == 0) ? f0_ : 0.f; acc[0][1] += (t_ == 0) ? f1_ : 0.f; \
    acc[1][0] += (t_ == 1) ? f0_ : 0.f; acc[1][1] += (t_ == 1) ? f1_ : 0.f; \
    acc[2][0] += (t_ == 2) ? f0_ : 0.f; acc[2][1] += (t_ == 2) ? f1_ : 0.f; \
    acc[3][0] += (t_ == 3) ? f0_ : 0.f; acc[3][1] += (t_ == 3) ? f1_ : 0.f; }
            for (; j + 12 < j1; j += 16) {
                int p0 = epay[j], p1 = epay[j + 4], p2 = epay[j + 8], p3 = epay[j + 12];
                unsigned int v0 = hbu[(size_t)(p0 & 0xffff) * 64 + lane];
                unsigned int v1 = hbu[(size_t)(p1 & 0xffff) * 64 + lane];
                unsigned int v2 = hbu[(size_t)(p2 & 0xffff) * 64 + lane];
                unsigned int v3 = hbu[(size_t)(p3 & 0xffff) * 64 + lane];
                AGG_ACC(p0, v0); AGG_ACC(p1, v1); AGG_ACC(p2, v2); AGG_ACC(p3, v3);
            }
            for (; j < j1; j += 4) {
                int p = epay[j];
                unsigned int v = hbu[(size_t)(p & 0xffff) * 64 + lane];
                AGG_ACC(p, v);
            }
#pragma unroll
            for (int t = 0; t < 4; t++) {
                smem[(wave * 4 + t) * 128 + 2 * lane]     = acc[t][0];
                smem[(wave * 4 + t) * 128 + 2 * lane + 1] = acc[t][1];
            }
            __syncthreads();
            int t = tid >> 6, l2 = tid & 63;
            float s0 = 0.f, s1 = 0.f;
#pragma unroll
            for (int w = 0; w < 4; w++) {
                s0 += smem[(w * 4 + t) * 128 + 2 * l2];
                s1 += smem[(w * 4 + t) * 128 + 2 * l2 + 1];
            }
            aggbu[((size_t)t * N2 + d) * 64 + l2] =
                (unsigned int)f2bf(s0) | ((unsigned int)f2bf(s1) << 16);
            __syncthreads();
        }
    }
    gbar(4, leaf, root, flag);

    // ===== Phase G: MFMA transform + log-softmax =====
    if (b < 94) {
        int row0 = b * 64;
        int wave = tid >> 6, lane = tid & 63;
        int r = row0 + wave * 16 + (lane & 15);
        int rl = (r < N2) ? r : N2 - 1;
        int kb = (lane >> 4) * 8;
        f32x4 acc[4] = {};
#pragma unroll
        for (int kt = 0; kt < 4; kt++) {
#pragma unroll
            for (int g = 0; g < 5; g++) {
                bfrag8 a;
                if (g < 4) {
                    a = *reinterpret_cast<const bfrag8*>(aggb + ((size_t)(g * N2 + rl) * D + kt * 32 + kb));
                } else {
                    bfrag8 raw = *reinterpret_cast<const bfrag8*>(hb + ((size_t)rl * D + kt * 32 + kb));
#pragma unroll
                    for (int j = 0; j < 8; j++) {
                        int c = kt * 32 + kb + j;
                        float f = bf2f((unsigned int)(unsigned short)raw[j]);
                        f = fmaxf(f * params[c] + params[128 + c], 0.f);
                        a[j] = (short)f2bf(f);
                    }
                }
#pragma unroll
                for (int ct = 0; ct < 4; ct++) {
                    bfrag8 bb = *reinterpret_cast<const bfrag8*>(BF + ((((g * 4 + kt) * 4 + ct) * 64 + lane) * 8));
                    acc[ct] = __builtin_amdgcn_mfma_f32_16x16x32_bf16(a, bb, acc[ct], 0, 0, 0);
                }
            }
        }
        float bb4[4];
#pragma unroll
        for (int ct = 0; ct < 4; ct++) bb4[ct] = b2[ct * 16 + (lane & 15)];
        int srow = row0 + wave * 16 + (lane >> 4) * 4;
#pragma unroll
        for (int i = 0; i < 4; i++) {
            float v[4];
#pragma unroll
            for (int ct = 0; ct < 4; ct++) v[ct] = acc[ct][i] + bb4[ct];
            float m = fmaxf(fmaxf(v[0], v[1]), fmaxf(v[2], v[3]));
#pragma unroll
            for (int sh = 1; sh <= 8; sh <<= 1) m = fmaxf(m, __shfl_xor(m, sh, 64));
            float s = 0.f;
#pragma unroll
            for (int ct = 0; ct < 4; ct++) s += expf(v[ct] - m);
#pragma unroll
            for (int sh = 1; sh <= 8; sh <<= 1) s += __shfl_xor(s, sh, 64);
            float lg = m + logf(s);
            int rr = srow + i;
            if (rr < N2) {
#pragma unroll
                for (int ct = 0; ct < 4; ct++)
                    out[(size_t)rr * DO + ct * 16 + (lane & 15)] = v[ct] - lg;
            }
        }
    }
}

extern "C" void kernel_launch(void* const* d_in, const int* in_sizes, int n_in,
                              void* d_out, int out_size, void* d_ws, size_t ws_size,
                              hipStream_t stream) {
    const float* x      = (const float*)d_in[0];
    const int* src1     = (const int*)d_in[1];
    const int* dst1     = (const int*)d_in[2];
    const int* et1      = (const int*)d_in[3];
    const int* src2     = (const int*)d_in[4];
    const int* dst2     = (const int*)d_in[5];
    const int* et2      = (const int*)d_in[6];
    const int* hmap     = (const int*)d_in[7];
    const float* hist   = (const float*)d_in[8];
    const float* W1     = (const float*)d_in[9];
    const float* Wself1 = (const float*)d_in[10];
    const float* b1     = (const float*)d_in[11];
    const float* gamma  = (const float*)d_in[12];
    const float* beta   = (const float*)d_in[13];
    const float* W2     = (const float*)d_in[14];
    const float* Wself2 = (const float*)d_in[15];
    const float* b2     = (const float*)d_in[16];
    float* out = (float*)d_out;

    char* ws = (char*)d_ws;
    unsigned short* hb   = (unsigned short*)(ws);              // 15,360,000
    unsigned short* aggb = (unsigned short*)(ws + 15360000);   //  6,144,000
    unsigned short* BF   = (unsigned short*)(ws + 21504000);   //     81,920
    float* hfix          = (float*)(ws + 21585920);            //    131,072
    int* uc_node         = (int*)(ws + 21716992);              //      1,024
    int* uc_slot         = (int*)(ws + 21718016);              //    240,000
    int* epay            = (int*)(ws + 21958016);              //  1,200,000
    int* rs              = (int*)(ws + 23158016);              //     24,016
    int* rs2             = (int*)(ws + 23182032);              //     24,000
    float* psum          = (float*)(ws + 23206032);            //    262,144
    float* statsfix      = (float*)(ws + 23468176);            //      1,024
    int* cnt             = (int*)(ws + 23469200);              //          4
    int* nuc             = (int*)(ws + 23469204);              //          4 (+pad)
    int* ehist           = (int*)(ws + 23469216);              //     24,000
    int* list            = (int*)(ws + 23493216);              //    131,072
    float* params        = (float*)(ws + 23624288);            //      1,024
    int* bar             = (int*)(ws + 23625312);              //      1,344

    k_pre<<<8, 256, 0, stream>>>(statsfix, cnt, nuc, ehist, bar);
    k_main<<<GRID, BLK, 0, stream>>>(x, src1, dst1, et1, src2, dst2, et2,
                                     hmap, hist, W1, Wself1, b1, gamma, beta,
                                     W2, Wself2, b2,
                                     hb, aggb, BF, hfix, uc_node, uc_slot,
                                     epay, rs, rs2, psum, statsfix,
                                     cnt, nuc, ehist, list, params, bar, out);
}

// Round 7
// 695.786 us; speedup vs baseline: 2.3040x; 2.3040x over previous
//
#include <hip/hip_runtime.h>
#include <hip/hip_bf16.h>

#define N0 300000
#define N1 60000
#define N2 6000
#define E1 1200000
#define E2 300000
#define D 128
#define DO 64

#define WL_CAP 32768
#define UC_CAP 256
#define GRID 1024
#define BLK 256

typedef __attribute__((ext_vector_type(8))) short bfrag8;
typedef __attribute__((ext_vector_type(4))) float f32x4;

__device__ __forceinline__ float bf2f(unsigned int u) {
    union { unsigned int i; float f; } c; c.i = u << 16; return c.f;
}
__device__ __forceinline__ unsigned short f2bf(float f) {
    return __bfloat16_as_ushort(__float2bfloat16(f));
}

// Device-scope tree barrier. RELAXED spin (no per-poll cache invalidate);
// one __threadfence() before (release) and after (acquire) per barrier.
__device__ __forceinline__ void gbar(int i, int* __restrict__ bar) {
    int* leaf = bar;            // [4][64]
    int* root = bar + 256;      // [4]
    int* flag = bar + 264;      // [4]
    __threadfence();
    __syncthreads();
    if (threadIdx.x == 0) {
        int l = blockIdx.x & 63;
        int lo = __hip_atomic_fetch_add(&leaf[i * 64 + l], 1,
                                        __ATOMIC_RELAXED, __HIP_MEMORY_SCOPE_AGENT);
        if (lo == (GRID / 64) - 1) {
            int ro = __hip_atomic_fetch_add(&root[i], 1,
                                            __ATOMIC_RELAXED, __HIP_MEMORY_SCOPE_AGENT);
            if (ro == 63)
                __hip_atomic_store(&flag[i], 1, __ATOMIC_RELAXED, __HIP_MEMORY_SCOPE_AGENT);
        }
        while (__hip_atomic_load(&flag[i], __ATOMIC_RELAXED, __HIP_MEMORY_SCOPE_AGENT) == 0)
            __builtin_amdgcn_s_sleep(10);
    }
    __syncthreads();
    __threadfence();
}

// ---- zero accumulators + barrier state (every call; graph-replay safe) ----
__global__ void k_pre(float* __restrict__ statsfix, int* __restrict__ cnt,
                      int* __restrict__ nuc, int* __restrict__ ehist,
                      int* __restrict__ bar) {
    int b = blockIdx.x, t = threadIdx.x;
    if (b == 0) {
        statsfix[t] = 0.f;
        if (t == 0) { *cnt = 0; *nuc = 0; }
        for (int i = t; i < 336; i += 256) bar[i] = 0;
    }
    int hi = (b + 1) * 750; if (hi > N2) hi = N2;
    for (int i = b * 750 + t; i < hi; i += 256) ehist[i] = 0;
}

__global__ void __launch_bounds__(BLK, 4) k_main(
        const float* __restrict__ x, const int* __restrict__ src1,
        const int* __restrict__ dst1, const int* __restrict__ et1,
        const int* __restrict__ src2, const int* __restrict__ dst2,
        const int* __restrict__ et2, const int* __restrict__ hmap,
        const float* __restrict__ hist, const float* __restrict__ W1,
        const float* __restrict__ Wself1, const float* __restrict__ b1,
        const float* __restrict__ gamma, const float* __restrict__ beta,
        const float* __restrict__ W2, const float* __restrict__ Wself2,
        const float* __restrict__ b2,
        unsigned short* __restrict__ hb, unsigned short* __restrict__ aggb,
        unsigned short* __restrict__ BF, float* __restrict__ hfix,
        int* __restrict__ uc_node, int* __restrict__ uc_slot,
        int* __restrict__ epay, int* __restrict__ rs, int* __restrict__ rs2,
        float* __restrict__ psum, float* __restrict__ psum2,
        float* __restrict__ statsfix,
        int* __restrict__ cnt, int* __restrict__ nuc, int* __restrict__ ehist,
        int* __restrict__ list, float* __restrict__ params,
        int* __restrict__ bar, float* __restrict__ out) {
    __shared__ float smem[2048];
    __shared__ int part[256];
    int b = blockIdx.x, tid = threadIdx.x;

    // ===== Phase B: [0,512) init hb + stats partials; [512,1024) scan+hist;
    //                [512,672) also pack B fragments =====
    if (b < 512) {
        int lane = tid & 63, q = tid & 31;
        float a1[4] = {0.f,0.f,0.f,0.f}, a2[4] = {0.f,0.f,0.f,0.f};
        for (int vb = b; vb < 1875; vb += 512) {
#pragma unroll
            for (int it = 0; it < 4; it++) {
                int idx = (vb * 4 + it) * 256 + tid;
                int node = idx >> 5;
                int m = hmap[node];
                float v[4];
                if (m >= 0) {
                    float4 hv = ((const float4*)hist)[m * 32 + q];
                    v[0] = hv.x; v[1] = hv.y; v[2] = hv.z; v[3] = hv.w;
                } else {
                    int slot = -1;
                    if (q == 0) {
                        slot = atomicAdd(nuc, 1);
                        if (slot < UC_CAP) { uc_slot[node] = slot; uc_node[slot] = node; }
                    }
                    slot = __shfl(slot, lane & 32, 64);
#pragma unroll
                    for (int j = 0; j < 4; j++) v[j] = b1[q * 4 + j];
                    for (int k = 0; k < D; k++) {
                        float xv = x[(size_t)node * D + k];
#pragma unroll
                        for (int j = 0; j < 4; j++) v[j] += xv * Wself1[k * D + q * 4 + j];
                    }
                    if (slot >= 0 && slot < UC_CAP) {
#pragma unroll
                        for (int j = 0; j < 4; j++) hfix[slot * D + q * 4 + j] = v[j];
                    }
                }
#pragma unroll
                for (int j = 0; j < 4; j++) { a1[j] += v[j]; a2[j] += v[j] * v[j]; }
                union { unsigned short s[4]; uint2 u; } o;
#pragma unroll
                for (int j = 0; j < 4; j++) o.s[j] = f2bf(v[j]);
                *(uint2*)(hb + (size_t)idx * 4) = o.u;
            }
        }
#pragma unroll
        for (int j = 0; j < 4; j++) { smem[tid * 4 + j] = a1[j]; smem[1024 + tid * 4 + j] = a2[j]; }
        __syncthreads();
        if (tid < 128) {
            int qq = tid >> 2, jj = tid & 3;
            float S = 0.f, SS = 0.f;
#pragma unroll
            for (int g = 0; g < 8; g++) {
                int src = (qq + 32 * g) * 4 + jj;
                S += smem[src]; SS += smem[1024 + src];
            }
            psum[b * 256 + tid] = S;
            psum[b * 256 + 128 + tid] = SS;
        }
    } else {
        for (int vb = b - 512; vb < 4688; vb += 512) {
            int e = vb * 256 + tid;
            if (e < E2) atomicAdd(&ehist[dst2[e]], 1);
            if (e < E1 && hmap[dst1[e]] < 0) {
                int i = atomicAdd(cnt, 1);
                if (i < WL_CAP) list[i] = e;
            }
        }
        if (b < 672) {
            int idx = (b - 512) * 256 + tid;     // 40960 exactly
            int j = idx & 7, lane = (idx >> 3) & 63, sub = (idx >> 9) & 15, g = idx >> 13;
            int kt = sub >> 2, ct = sub & 3;
            int k = kt * 32 + (lane >> 4) * 8 + j;
            int col = ct * 16 + (lane & 15);
            float v = (g < 4) ? W2[(g * D + k) * DO + col] : Wself2[k * DO + col];
            BF[idx] = f2bf(v);
        }
    }
    gbar(0, bar);

    // ===== Phase C: [0,16) worklist; 16: escan; [32,64): psum reduce =====
    if (b < 16) {
        int c = tid & 127, half = tid >> 7;
        int n = *cnt; if (n > WL_CAP) n = WL_CAP;
        for (int i = b * 2 + half; i < n; i += 32) {
            int e = list[i];
            int s = src1[e], d = dst1[e], t = et1[e];
            int slot = uc_slot[d];
            if (slot < 0 || slot >= UC_CAP) continue;
            float acc = 0.f;
            for (int k = 0; k < D; k++) acc += x[(size_t)s * D + k] * W1[(t * D + k) * D + c];
            float old = atomicAdd(&hfix[slot * D + c], acc);
            atomicAdd(&statsfix[c], acc);
            atomicAdd(&statsfix[128 + c], 2.f * old * acc + acc * acc);
        }
    } else if (b == 16) {
        int lo = tid * 24, hi = lo + 24; if (hi > N2) hi = N2;
        int s = 0;
        for (int i = lo; i < hi; i++) s += ehist[i];
        part[tid] = s;
        __syncthreads();
        if (tid == 0) {
            int a = 0;
            for (int i = 0; i < 256; i++) { int v = part[i]; part[i] = a; a += v; }
            rs[N2] = a;
        }
        __syncthreads();
        int a = part[tid];
        for (int i = lo; i < hi; i++) { rs[i] = a; rs2[i] = a; a += ehist[i]; }
    } else if (b >= 32 && b < 64) {
        int r = b - 32;
        float S = 0.f;
        for (int i = 0; i < 16; i++) S += psum[(r * 16 + i) * 256 + tid];
        psum2[r * 256 + tid] = S;
    }
    gbar(1, bar);

    // ===== Phase D: params | uc-copy | escatter (all blocks) =====
    if (b == 0) {
        if (tid < 128) {
            float S = statsfix[tid], SS = statsfix[128 + tid];
#pragma unroll
            for (int r = 0; r < 32; r++) {
                S += psum2[r * 256 + tid];
                SS += psum2[r * 256 + 128 + tid];
            }
            float mean = S / (float)N1;
            float var = SS / (float)N1 - mean * mean;
            float sc = gamma[tid] * rsqrtf(var + 1e-5f);
            params[tid] = sc;
            params[128 + tid] = beta[tid] - mean * sc;
        }
    } else if (b >= 162 && b < 170) {
        int n = *nuc; if (n > UC_CAP) n = UC_CAP;
        int c = tid & 127, sub = tid >> 7;
        for (int slot = (b - 162) * 2 + sub; slot < n; slot += 16)
            hb[(size_t)uc_node[slot] * D + c] = f2bf(hfix[slot * D + c]);
    }
    for (int e = b * 256 + tid; e < E2; e += GRID * 256) {
        int d = dst2[e];
        int pos = atomicAdd(&rs2[d], 1);
        epay[pos] = src2[e] | (et2[e] << 16);
    }
    gbar(2, bar);

    // ===== Phase F: aggregate (block-per-dst, grid-stride) =====
    {
        int wave = tid >> 6, lane = tid & 63;
        float sc0 = params[2 * lane],     sh0 = params[128 + 2 * lane];
        float sc1 = params[2 * lane + 1], sh1 = params[128 + 2 * lane + 1];
        const unsigned int* hbu = (const unsigned int*)hb;
        unsigned int* aggbu = (unsigned int*)aggb;
        for (int d = b; d < N2; d += GRID) {
            float acc[4][2] = {};
            int j0 = rs[d], j1 = rs[d + 1];
            int j = j0 + wave;
#define AGG_ACC(P, V) { \
    int t_ = (P) >> 16; \
    float f0_ = fmaxf(bf2f((V) & 0xffff) * sc0 + sh0, 0.f); \
    float f1_ = fmaxf(bf2f((V) >> 16) * sc1 + sh1, 0.f); \
    acc[0][0] += (t_ == 0) ? f0_ : 0.f; acc[0][1] += (t_ == 0) ? f1_ : 0.f; \
    acc[1][0] += (t_ == 1) ? f0_ : 0.f; acc[1][1] += (t_ == 1) ? f1_ : 0.f; \
    acc[2][0] += (t_ == 2) ? f0_ : 0.f; acc[2][1] += (t_ == 2) ? f1_ : 0.f; \
    acc[3][0] += (t_ == 3) ? f0_ : 0.f; acc[3][1] += (t_ == 3) ? f1_ : 0.f; }
            for (; j + 12 < j1; j += 16) {
                int p0 = epay[j], p1 = epay[j + 4], p2 = epay[j + 8], p3 = epay[j + 12];
                unsigned int v0 = hbu[(size_t)(p0 & 0xffff) * 64 + lane];
                unsigned int v1 = hbu[(size_t)(p1 & 0xffff) * 64 + lane];
                unsigned int v2 = hbu[(size_t)(p2 & 0xffff) * 64 + lane];
                unsigned int v3 = hbu[(size_t)(p3 & 0xffff) * 64 + lane];
                AGG_ACC(p0, v0); AGG_ACC(p1, v1); AGG_ACC(p2, v2); AGG_ACC(p3, v3);
            }
            for (; j < j1; j += 4) {
                int p = epay[j];
                unsigned int v = hbu[(size_t)(p & 0xffff) * 64 + lane];
                AGG_ACC(p, v);
            }
#pragma unroll
            for (int t = 0; t < 4; t++) {
                smem[(wave * 4 + t) * 128 + 2 * lane]     = acc[t][0];
                smem[(wave * 4 + t) * 128 + 2 * lane + 1] = acc[t][1];
            }
            __syncthreads();
            int t = tid >> 6, l2 = tid & 63;
            float s0 = 0.f, s1 = 0.f;
#pragma unroll
            for (int w = 0; w < 4; w++) {
                s0 += smem[(w * 4 + t) * 128 + 2 * l2];
                s1 += smem[(w * 4 + t) * 128 + 2 * l2 + 1];
            }
            aggbu[((size_t)t * N2 + d) * 64 + l2] =
                (unsigned int)f2bf(s0) | ((unsigned int)f2bf(s1) << 16);
            __syncthreads();
        }
    }
    gbar(3, bar);

    // ===== Phase G: MFMA transform + log-softmax =====
    if (b < 94) {
        int row0 = b * 64;
        int wave = tid >> 6, lane = tid & 63;
        int r = row0 + wave * 16 + (lane & 15);
        int rl = (r < N2) ? r : N2 - 1;
        int kb = (lane >> 4) * 8;
        f32x4 acc[4] = {};
#pragma unroll
        for (int kt = 0; kt < 4; kt++) {
#pragma unroll
            for (int g = 0; g < 5; g++) {
                bfrag8 a;
                if (g < 4) {
                    a = *reinterpret_cast<const bfrag8*>(aggb + ((size_t)(g * N2 + rl) * D + kt * 32 + kb));
                } else {
                    bfrag8 raw = *reinterpret_cast<const bfrag8*>(hb + ((size_t)rl * D + kt * 32 + kb));
#pragma unroll
                    for (int j = 0; j < 8; j++) {
                        int c = kt * 32 + kb + j;
                        float f = bf2f((unsigned int)(unsigned short)raw[j]);
                        f = fmaxf(f * params[c] + params[128 + c], 0.f);
                        a[j] = (short)f2bf(f);
                    }
                }
#pragma unroll
                for (int ct = 0; ct < 4; ct++) {
                    bfrag8 bb = *reinterpret_cast<const bfrag8*>(BF + ((((g * 4 + kt) * 4 + ct) * 64 + lane) * 8));
                    acc[ct] = __builtin_amdgcn_mfma_f32_16x16x32_bf16(a, bb, acc[ct], 0, 0, 0);
                }
            }
        }
        float bb4[4];
#pragma unroll
        for (int ct = 0; ct < 4; ct++) bb4[ct] = b2[ct * 16 + (lane & 15)];
        int srow = row0 + wave * 16 + (lane >> 4) * 4;
#pragma unroll
        for (int i = 0; i < 4; i++) {
            float v[4];
#pragma unroll
            for (int ct = 0; ct < 4; ct++) v[ct] = acc[ct][i] + bb4[ct];
            float m = fmaxf(fmaxf(v[0], v[1]), fmaxf(v[2], v[3]));
#pragma unroll
            for (int sh = 1; sh <= 8; sh <<= 1) m = fmaxf(m, __shfl_xor(m, sh, 64));
            float s = 0.f;
#pragma unroll
            for (int ct = 0; ct < 4; ct++) s += expf(v[ct] - m);
#pragma unroll
            for (int sh = 1; sh <= 8; sh <<= 1) s += __shfl_xor(s, sh, 64);
            float lg = m + logf(s);
            int rr = srow + i;
            if (rr < N2) {
#pragma unroll
                for (int ct = 0; ct < 4; ct++)
                    out[(size_t)rr * DO + ct * 16 + (lane & 15)] = v[ct] - lg;
            }
        }
    }
}

extern "C" void kernel_launch(void* const* d_in, const int* in_sizes, int n_in,
                              void* d_out, int out_size, void* d_ws, size_t ws_size,
                              hipStream_t stream) {
    const float* x      = (const float*)d_in[0];
    const int* src1     = (const int*)d_in[1];
    const int* dst1     = (const int*)d_in[2];
    const int* et1      = (const int*)d_in[3];
    const int* src2     = (const int*)d_in[4];
    const int* dst2     = (const int*)d_in[5];
    const int* et2      = (const int*)d_in[6];
    const int* hmap     = (const int*)d_in[7];
    const float* hist   = (const float*)d_in[8];
    const float* W1     = (const float*)d_in[9];
    const float* Wself1 = (const float*)d_in[10];
    const float* b1     = (const float*)d_in[11];
    const float* gamma  = (const float*)d_in[12];
    const float* beta   = (const float*)d_in[13];
    const float* W2     = (const float*)d_in[14];
    const float* Wself2 = (const float*)d_in[15];
    const float* b2     = (const float*)d_in[16];
    float* out = (float*)d_out;

    char* ws = (char*)d_ws;
    unsigned short* hb   = (unsigned short*)(ws);              // 15,360,000
    unsigned short* aggb = (unsigned short*)(ws + 15360000);   //  6,144,000
    unsigned short* BF   = (unsigned short*)(ws + 21504000);   //     81,920
    float* hfix          = (float*)(ws + 21585920);            //    131,072
    int* uc_node         = (int*)(ws + 21716992);              //      1,024
    int* uc_slot         = (int*)(ws + 21718016);              //    240,000
    int* epay            = (int*)(ws + 21958016);              //  1,200,000
    int* rs              = (int*)(ws + 23158016);              //     24,016
    int* rs2             = (int*)(ws + 23182032);              //     24,000
    float* psum          = (float*)(ws + 23206032);            //    524,288
    float* psum2         = (float*)(ws + 23730320);            //     32,768
    float* statsfix      = (float*)(ws + 23763088);            //      1,024
    int* cnt             = (int*)(ws + 23764112);              //          4
    int* nuc             = (int*)(ws + 23764116);              //          4 (+pad)
    int* ehist           = (int*)(ws + 23764128);              //     24,000
    int* list            = (int*)(ws + 23788128);              //    131,072
    float* params        = (float*)(ws + 23919200);            //      1,024
    int* bar             = (int*)(ws + 23920224);              //      1,344

    k_pre<<<8, 256, 0, stream>>>(statsfix, cnt, nuc, ehist, bar);
    k_main<<<GRID, BLK, 0, stream>>>(x, src1, dst1, et1, src2, dst2, et2,
                                     hmap, hist, W1, Wself1, b1, gamma, beta,
                                     W2, Wself2, b2,
                                     hb, aggb, BF, hfix, uc_node, uc_slot,
                                     epay, rs, rs2, psum, psum2, statsfix,
                                     cnt, nuc, ehist, list, params, bar, out);
}